// Round 1
// baseline (145.634 us; speedup 1.0000x reference)
//
#include <hip/hip_runtime.h>
#include <cfloat>

// Problem constants (fixed by the reference): B=8, N=4096, NUM_CLASS=13, C=3.
constexpr int Bb    = 8;
constexpr int Nn    = 4096;
constexpr int NC    = 13;
constexpr int TJ    = 1024;   // j-tile staged in LDS (16 KB as float4)
constexpr int BLOCK = 256;

// Grid = 256 blocks: blk>>7 = direction (0: x=point_rec,y=point ; 1: swapped),
// (blk&127) = batch*16 + i-chunk. Each thread owns one query point i and
// min-reduces squared distance over all 4096 target points j.
// Dir-0 blocks additionally gather the NLL seg-loss term (32768 threads = B*N).
__global__ __launch_bounds__(BLOCK)
void criterion_kernel(const float* __restrict__ seg_prob,
                      const int*   __restrict__ seg_label,
                      const float* __restrict__ point_rec,
                      const float* __restrict__ point,
                      float*       __restrict__ out) {
    __shared__ float4 ytile[TJ];
    __shared__ float  wsum[BLOCK / 64];

    const int blk   = blockIdx.x;
    const int dir   = blk >> 7;
    const int sub   = blk & 127;
    const int b     = sub >> 4;
    const int chunk = sub & 15;
    const int t     = threadIdx.x;
    const int i     = chunk * BLOCK + t;

    const float* __restrict__ xb =
        (dir ? point : point_rec) + ((size_t)b * Nn + i) * 3;
    const float* __restrict__ yb =
        (dir ? point_rec : point) + (size_t)b * Nn * 3;

    const float xi0 = xb[0], xi1 = xb[1], xi2 = xb[2];

    // 4 independent min accumulators -> breaks the serial v_min chain
    // (we run at ~1 wave/SIMD, so ILP must come from within the thread).
    float m0 = FLT_MAX, m1 = FLT_MAX, m2 = FLT_MAX, m3 = FLT_MAX;

    for (int jt = 0; jt < Nn; jt += TJ) {
        // Stage TJ target points into LDS as padded float4 (one b128 read/j).
        for (int p = t; p < TJ; p += BLOCK) {
            const float* yp = yb + (size_t)(jt + p) * 3;
            ytile[p] = make_float4(yp[0], yp[1], yp[2], 0.0f);
        }
        __syncthreads();

        #pragma unroll 8
        for (int j = 0; j < TJ; j += 4) {
            float4 p0 = ytile[j + 0];
            float4 p1 = ytile[j + 1];
            float4 p2 = ytile[j + 2];
            float4 p3 = ytile[j + 3];

            float dx, dy, dz, d;
            dx = xi0 - p0.x; dy = xi1 - p0.y; dz = xi2 - p0.z;
            d = dx * dx + dy * dy + dz * dz;
            m0 = fminf(m0, d);

            dx = xi0 - p1.x; dy = xi1 - p1.y; dz = xi2 - p1.z;
            d = dx * dx + dy * dy + dz * dz;
            m1 = fminf(m1, d);

            dx = xi0 - p2.x; dy = xi1 - p2.y; dz = xi2 - p2.z;
            d = dx * dx + dy * dy + dz * dz;
            m2 = fminf(m2, d);

            dx = xi0 - p3.x; dy = xi1 - p3.y; dz = xi2 - p3.z;
            d = dx * dx + dy * dy + dz * dz;
            m3 = fminf(m3, d);
        }
        __syncthreads();
    }

    float v = fminf(fminf(m0, m1), fminf(m2, m3));

    // NLL seg-loss: dir-0 blocks cover gi = 0..B*N-1 exactly once.
    // Same 1/(B*N) scale as the chamfer means, so just add into v.
    if (dir == 0) {
        const int gi = sub * BLOCK + t;
        v -= seg_prob[(size_t)gi * NC + (size_t)seg_label[gi]];
    }

    // Block reduction: wave-64 shuffle, then across the 4 waves via LDS.
    for (int off = 32; off > 0; off >>= 1)
        v += __shfl_down(v, off, 64);
    if ((t & 63) == 0) wsum[t >> 6] = v;
    __syncthreads();
    if (t == 0) {
        float s = wsum[0] + wsum[1] + wsum[2] + wsum[3];
        atomicAdd(out, s * (1.0f / (Bb * Nn)));
    }
}

extern "C" void kernel_launch(void* const* d_in, const int* in_sizes, int n_in,
                              void* d_out, int out_size, void* d_ws, size_t ws_size,
                              hipStream_t stream) {
    const float* seg_prob  = (const float*)d_in[0];
    const int*   seg_label = (const int*)d_in[1];
    const float* point_rec = (const float*)d_in[2];
    const float* point     = (const float*)d_in[3];
    float*       out       = (float*)d_out;

    // d_out is re-poisoned to 0xAA before every timed launch; zero it.
    hipMemsetAsync(out, 0, sizeof(float), stream);
    criterion_kernel<<<dim3(256), dim3(BLOCK), 0, stream>>>(
        seg_prob, seg_label, point_rec, point, out);
}

// Round 2
// 99.220 us; speedup vs baseline: 1.4678x; 1.4678x over previous
//
#include <hip/hip_runtime.h>
#include <cfloat>

// Problem constants (fixed by the reference): B=8, N=4096, NUM_CLASS=13, C=3.
constexpr int Bb    = 8;
constexpr int Nn    = 4096;
constexpr int NC    = 13;
constexpr int JP    = 4;      // j-range split factor (occupancy)
constexpr int TJ    = Nn / JP; // 1024 j's per block, staged once in LDS (16 KB)
constexpr int BLOCK = 256;
constexpr int CHUNKS = Nn / BLOCK; // 16 i-chunks
constexpr int NPTS  = 2 * Bb * Nn; // 65536 (dir, b, i) query points

// Kernel 1: grid = 2*8*16*4 = 1024 blocks.
// blk decode: part = blk&3 (fastest), chunk, b, dir.
// Each thread owns query point i, min-reduces t_j = (yy_j - 2*x.y_j) over its
// 1024-j part, writes partial min to ws[part*NPTS + g]. xx_i drops out of the
// min (constant per thread) and is sum-reduced by part-0 blocks along with the
// NLL seg term (dir-0 part-0 blocks cover gi = 0..B*N-1 exactly once).
__global__ __launch_bounds__(BLOCK)
void chamfer_partial_kernel(const float* __restrict__ seg_prob,
                            const int*   __restrict__ seg_label,
                            const float* __restrict__ point_rec,
                            const float* __restrict__ point,
                            float*       __restrict__ ws,
                            float*       __restrict__ out) {
    __shared__ float4 ytile[TJ];
    __shared__ float  wsum[BLOCK / 64];

    const int blk   = blockIdx.x;
    const int part  = blk & (JP - 1);
    const int chunk = (blk >> 2) & (CHUNKS - 1);
    const int b     = (blk >> 6) & (Bb - 1);
    const int dir   = blk >> 9;
    const int t     = threadIdx.x;
    const int i     = chunk * BLOCK + t;

    const float* __restrict__ xb =
        (dir ? point : point_rec) + ((size_t)b * Nn + i) * 3;
    const float* __restrict__ yb =
        (dir ? point_rec : point) + ((size_t)b * Nn + part * TJ) * 3;

    const float xi0 = xb[0], xi1 = xb[1], xi2 = xb[2];

    // Stage this part's TJ target points; w slot = |y|^2 (precomputed once).
    for (int p = t; p < TJ; p += BLOCK) {
        const float* yp = yb + (size_t)p * 3;
        const float y0 = yp[0], y1 = yp[1], y2 = yp[2];
        ytile[p] = make_float4(y0, y1, y2, y0 * y0 + y1 * y1 + y2 * y2);
    }
    __syncthreads();

    // 4 independent min accumulators for ILP. Per j: mul + 2*fma + fma + min.
    float m0 = FLT_MAX, m1 = FLT_MAX, m2 = FLT_MAX, m3 = FLT_MAX;

    #pragma unroll 8
    for (int j = 0; j < TJ; j += 4) {
        float4 p0 = ytile[j + 0];
        float4 p1 = ytile[j + 1];
        float4 p2 = ytile[j + 2];
        float4 p3 = ytile[j + 3];

        float s;
        s = fmaf(xi2, p0.z, fmaf(xi1, p0.y, xi0 * p0.x));
        m0 = fminf(m0, fmaf(-2.0f, s, p0.w));
        s = fmaf(xi2, p1.z, fmaf(xi1, p1.y, xi0 * p1.x));
        m1 = fminf(m1, fmaf(-2.0f, s, p1.w));
        s = fmaf(xi2, p2.z, fmaf(xi1, p2.y, xi0 * p2.x));
        m2 = fminf(m2, fmaf(-2.0f, s, p2.w));
        s = fmaf(xi2, p3.z, fmaf(xi1, p3.y, xi0 * p3.x));
        m3 = fminf(m3, fmaf(-2.0f, s, p3.w));
    }

    const int g = (dir * Bb + b) * Nn + i;  // 0..NPTS-1
    ws[(size_t)part * NPTS + g] = fminf(fminf(m0, m1), fminf(m2, m3));

    // Additive extras (xx + seg), only from part-0 blocks.
    if (part == 0) {
        float v = fmaf(xi2, xi2, fmaf(xi1, xi1, xi0 * xi0));  // xx_i
        if (dir == 0) {
            const int gi = b * Nn + i;
            v -= seg_prob[(size_t)gi * NC + (size_t)seg_label[gi]];
        }
        for (int off = 32; off > 0; off >>= 1)
            v += __shfl_down(v, off, 64);
        if ((t & 63) == 0) wsum[t >> 6] = v;
        __syncthreads();
        if (t == 0) {
            float s = wsum[0] + wsum[1] + wsum[2] + wsum[3];
            atomicAdd(out, s * (1.0f / (Bb * Nn)));
        }
    }
}

// Kernel 2: min the JP partials per query point, sum-reduce, atomicAdd.
__global__ __launch_bounds__(BLOCK)
void chamfer_combine_kernel(const float* __restrict__ ws,
                            float*       __restrict__ out) {
    __shared__ float wsum[BLOCK / 64];
    const int t = threadIdx.x;
    const int g = blockIdx.x * BLOCK + t;

    float m = ws[g];
    #pragma unroll
    for (int p = 1; p < JP; ++p)
        m = fminf(m, ws[(size_t)p * NPTS + g]);

    float v = m;
    for (int off = 32; off > 0; off >>= 1)
        v += __shfl_down(v, off, 64);
    if ((t & 63) == 0) wsum[t >> 6] = v;
    __syncthreads();
    if (t == 0) {
        float s = wsum[0] + wsum[1] + wsum[2] + wsum[3];
        atomicAdd(out, s * (1.0f / (Bb * Nn)));
    }
}

extern "C" void kernel_launch(void* const* d_in, const int* in_sizes, int n_in,
                              void* d_out, int out_size, void* d_ws, size_t ws_size,
                              hipStream_t stream) {
    const float* seg_prob  = (const float*)d_in[0];
    const int*   seg_label = (const int*)d_in[1];
    const float* point_rec = (const float*)d_in[2];
    const float* point     = (const float*)d_in[3];
    float*       out       = (float*)d_out;
    float*       ws        = (float*)d_ws;   // JP * NPTS floats = 1 MB

    hipMemsetAsync(out, 0, sizeof(float), stream);
    chamfer_partial_kernel<<<dim3(2 * Bb * CHUNKS * JP), dim3(BLOCK), 0, stream>>>(
        seg_prob, seg_label, point_rec, point, ws, out);
    chamfer_combine_kernel<<<dim3(NPTS / BLOCK), dim3(BLOCK), 0, stream>>>(ws, out);
}

// Round 3
// 81.723 us; speedup vs baseline: 1.7820x; 1.2141x over previous
//
#include <hip/hip_runtime.h>
#include <cfloat>

// Problem constants (fixed by the reference): B=8, N=4096, NUM_CLASS=13, C=3.
constexpr int Bb    = 8;
constexpr int Nn    = 4096;
constexpr int NC    = 13;
constexpr int JP    = 2;         // j-range split factor
constexpr int TJ    = Nn / JP;   // 2048 j's staged per block (32 KB LDS)
constexpr int BLOCK = 256;       // 4 waves; each wave owns 32 i's -> 128 i/block
constexpr int ICH   = Nn / 128;  // 32 i-chunks
constexpr int NPTS  = 2 * Bb * Nn; // 65536 query points

typedef __attribute__((ext_vector_type(8)))  short          short8;
typedef __attribute__((ext_vector_type(8)))  unsigned short ushort8;
typedef __attribute__((ext_vector_type(16))) float          floatx16;

// fp32 -> bf16 round-to-nearest-even (bit trick; inputs are finite).
static __device__ inline unsigned short f2bf(float f) {
    unsigned u = __builtin_bit_cast(unsigned, f);
    return (unsigned short)((u + 0x7FFFu + ((u >> 16) & 1u)) >> 16);
}
static __device__ inline float bf2f(unsigned short h) {
    return __builtin_bit_cast(float, (unsigned)h << 16);
}

// Kernel 1: grid = 2 dir * 8 b * 32 ichunk * 2 part = 1024 blocks.
// Per block: stage TJ=2048 target points into LDS as packed bf16 A-fragments
//   A[j] = {yh0, yh1, yh2, h1, h2, 0, 0, 0} where h1+h2 ~= |yhat|^2 (fp32 split).
// Per wave (32 i's): B-frag lanes 0-31 = {-2xh0,-2xh1,-2xh2, 1, 1, 0,0,0},
// lanes 32-63 = 0 (k=8..15 half). One v_mfma_f32_32x32x16_bf16 per 32-j tile
// gives t(j,i) = |yhat|^2 - 2 xhat.yhat in fp32; v_min3 chains reduce over j.
// xx (from rounded xhat) is constant per i -> dropped from the min, summed
// separately by part-0 blocks together with the NLL seg term.
__global__ __launch_bounds__(BLOCK)
void chamfer_mfma_kernel(const float* __restrict__ seg_prob,
                         const int*   __restrict__ seg_label,
                         const float* __restrict__ point_rec,
                         const float* __restrict__ point,
                         float*       __restrict__ ws,
                         float*       __restrict__ out) {
    __shared__ ushort8 ytile[TJ];          // 32 KB
    __shared__ float   wsum[BLOCK / 64];

    const int blk   = blockIdx.x;
    const int part  = blk & (JP - 1);
    const int chunk = (blk >> 1) & (ICH - 1);
    const int b     = (blk >> 6) & (Bb - 1);
    const int dir   = blk >> 9;
    const int t     = threadIdx.x;
    const int lane  = t & 63;
    const int wave  = t >> 6;
    const int l31   = lane & 31;

    const float* __restrict__ xbase =
        (dir ? point : point_rec) + (size_t)(b * Nn + chunk * 128) * 3;
    const float* __restrict__ ybase =
        (dir ? point_rec : point) + (size_t)(b * Nn + part * TJ) * 3;

    // ---- stage Y tile: 8 points per thread ----
    for (int p = t; p < TJ; p += BLOCK) {
        const float* yp = ybase + (size_t)p * 3;
        const unsigned short yh0 = f2bf(yp[0]);
        const unsigned short yh1 = f2bf(yp[1]);
        const unsigned short yh2 = f2bf(yp[2]);
        const float yf0 = bf2f(yh0), yf1 = bf2f(yh1), yf2 = bf2f(yh2);
        const float yy  = fmaf(yf2, yf2, fmaf(yf1, yf1, yf0 * yf0));
        const unsigned short h1 = f2bf(yy);
        const unsigned short h2 = f2bf(yy - bf2f(h1));
        ushort8 v;
        v[0] = yh0; v[1] = yh1; v[2] = yh2; v[3] = h1; v[4] = h2;
        v[5] = 0;   v[6] = 0;   v[7] = 0;
        ytile[p] = v;
    }

    // ---- build B fragment (this wave's 32 x-points, fixed for the kernel) ----
    const int   i_loc = wave * 32 + l31;           // 0..127 within chunk
    const float* xp   = xbase + (size_t)i_loc * 3;
    const unsigned short xh0 = f2bf(xp[0]);
    const unsigned short xh1 = f2bf(xp[1]);
    const unsigned short xh2 = f2bf(xp[2]);
    const bool lo = (lane < 32);
    ushort8 bu;
    bu[0] = lo ? f2bf(-2.0f * bf2f(xh0)) : (unsigned short)0;
    bu[1] = lo ? f2bf(-2.0f * bf2f(xh1)) : (unsigned short)0;
    bu[2] = lo ? f2bf(-2.0f * bf2f(xh2)) : (unsigned short)0;
    bu[3] = lo ? (unsigned short)0x3F80 : (unsigned short)0;   // bf16 1.0
    bu[4] = lo ? (unsigned short)0x3F80 : (unsigned short)0;
    bu[5] = 0; bu[6] = 0; bu[7] = 0;
    const short8 bfrag = __builtin_bit_cast(short8, bu);

    floatx16 zc;
    #pragma unroll
    for (int q = 0; q < 16; ++q) zc[q] = 0.0f;

    __syncthreads();

    // ---- main loop: 64 MFMAs over the 2048-j tile ----
    float m0 = FLT_MAX, m1 = FLT_MAX, m2 = FLT_MAX, m3 = FLT_MAX;
    #pragma unroll 4
    for (int jt = 0; jt < TJ / 32; ++jt) {
        // lanes 32-63 duplicate rows 0-31 (2-way broadcast, free); their k-half
        // multiplies B's zeroed upper half, so the garbage k=8..15 is harmless.
        const short8 af = __builtin_bit_cast(short8, ytile[jt * 32 + l31]);
        const floatx16 d =
            __builtin_amdgcn_mfma_f32_32x32x16_bf16(af, bfrag, zc, 0, 0, 0);
        m0 = fminf(fminf(d[0],  d[1]),  m0);
        m1 = fminf(fminf(d[2],  d[3]),  m1);
        m2 = fminf(fminf(d[4],  d[5]),  m2);
        m3 = fminf(fminf(d[6],  d[7]),  m3);
        m0 = fminf(fminf(d[8],  d[9]),  m0);
        m1 = fminf(fminf(d[10], d[11]), m1);
        m2 = fminf(fminf(d[12], d[13]), m2);
        m3 = fminf(fminf(d[14], d[15]), m3);
    }

    // per-lane min covers this half-wave's 16 rows per tile; combine halves.
    float mm = fminf(fminf(m0, m1), fminf(m2, m3));
    mm = fminf(mm, __shfl_xor(mm, 32, 64));
    if (lo) {
        const int g = (dir * Bb + b) * Nn + chunk * 128 + i_loc;
        ws[(size_t)part * NPTS + g] = mm;
    }

    // ---- additive extras: xx (rounded-x, consistent with B) + NLL seg ----
    if (part == 0) {
        float v = 0.0f;
        if (t < 128) {
            const float* xq = xbase + (size_t)t * 3;
            const float a0 = bf2f(f2bf(xq[0]));
            const float a1 = bf2f(f2bf(xq[1]));
            const float a2 = bf2f(f2bf(xq[2]));
            v = fmaf(a2, a2, fmaf(a1, a1, a0 * a0));
            if (dir == 0) {
                const int gi = b * Nn + chunk * 128 + t;
                v -= seg_prob[(size_t)gi * NC + (size_t)seg_label[gi]];
            }
        }
        for (int off = 32; off > 0; off >>= 1)
            v += __shfl_down(v, off, 64);
        if ((t & 63) == 0) wsum[t >> 6] = v;
        __syncthreads();
        if (t == 0) {
            float s = wsum[0] + wsum[1] + wsum[2] + wsum[3];
            atomicAdd(out, s * (1.0f / (Bb * Nn)));
        }
    }
}

// Kernel 2: min the JP partials per query point, sum-reduce, atomicAdd.
__global__ __launch_bounds__(BLOCK)
void chamfer_combine_kernel(const float* __restrict__ ws,
                            float*       __restrict__ out) {
    __shared__ float wsum[BLOCK / 64];
    const int t = threadIdx.x;
    const int g = blockIdx.x * BLOCK + t;

    float v = fminf(ws[g], ws[(size_t)NPTS + g]);
    for (int off = 32; off > 0; off >>= 1)
        v += __shfl_down(v, off, 64);
    if ((t & 63) == 0) wsum[t >> 6] = v;
    __syncthreads();
    if (t == 0) {
        float s = wsum[0] + wsum[1] + wsum[2] + wsum[3];
        atomicAdd(out, s * (1.0f / (Bb * Nn)));
    }
}

extern "C" void kernel_launch(void* const* d_in, const int* in_sizes, int n_in,
                              void* d_out, int out_size, void* d_ws, size_t ws_size,
                              hipStream_t stream) {
    const float* seg_prob  = (const float*)d_in[0];
    const int*   seg_label = (const int*)d_in[1];
    const float* point_rec = (const float*)d_in[2];
    const float* point     = (const float*)d_in[3];
    float*       out       = (float*)d_out;
    float*       ws        = (float*)d_ws;   // JP * NPTS floats = 512 KB

    hipMemsetAsync(out, 0, sizeof(float), stream);
    chamfer_mfma_kernel<<<dim3(2 * Bb * ICH * JP), dim3(BLOCK), 0, stream>>>(
        seg_prob, seg_label, point_rec, point, ws, out);
    chamfer_combine_kernel<<<dim3(NPTS / BLOCK), dim3(BLOCK), 0, stream>>>(ws, out);
}

// Round 4
// 80.519 us; speedup vs baseline: 1.8087x; 1.0150x over previous
//
#include <hip/hip_runtime.h>
#include <cfloat>

// Problem constants (fixed by the reference): B=8, N=4096, NUM_CLASS=13, C=3.
constexpr int Bb    = 8;
constexpr int Nn    = 4096;
constexpr int NC    = 13;
constexpr int BLOCK = 256;        // 4 waves; each wave owns 32 i's -> 128 i/block
constexpr int ICH   = Nn / 128;   // 32 i-chunks
// Grid = 2 dir * 8 b * 32 chunk = 512 blocks (2 blocks/CU, LDS-limited).

typedef __attribute__((ext_vector_type(8)))  short          short8;
typedef __attribute__((ext_vector_type(8)))  unsigned short ushort8;
typedef __attribute__((ext_vector_type(16))) float          floatx16;

// fp32 -> bf16 round-to-nearest-even (bit trick; inputs are finite).
static __device__ inline unsigned short f2bf(float f) {
    unsigned u = __builtin_bit_cast(unsigned, f);
    return (unsigned short)((u + 0x7FFFu + ((u >> 16) & 1u)) >> 16);
}
static __device__ inline float bf2f(unsigned short h) {
    return __builtin_bit_cast(float, (unsigned)h << 16);
}

// Single fused kernel.
// Per block: stage ALL 4096 target points into LDS as packed bf16 A-fragments
//   A[j] = {yh0, yh1, yh2, h1, h2, 0, 0, 0}, h1+h2 ~= |yhat|^2 (two-term split).
// Per wave (32 i's): B lanes 0-31 = {-2xh0,-2xh1,-2xh2, 1, 1, 0,0,0},
// lanes 32-63 = 0 (they feed the k=8..15 half, which must not contribute).
// One v_mfma_f32_32x32x16_bf16 per 32-j tile gives t(j,i) = yy - 2 x.y in
// fp32 (exact given bf16 inputs); v_min3 chains reduce over j per lane
// (16 rows/lane), shfl_xor(32) merges the complementary row halves.
// xx (rounded-x, consistent with B) is constant per i -> dropped from the min
// and added back in the block sum, together with the NLL seg gather (dir 0).
__global__ __launch_bounds__(BLOCK)
void criterion_fused_kernel(const float* __restrict__ seg_prob,
                            const int*   __restrict__ seg_label,
                            const float* __restrict__ point_rec,
                            const float* __restrict__ point,
                            float*       __restrict__ out) {
    __shared__ ushort8 ytile[Nn];          // 64 KB
    __shared__ float   wsum[BLOCK / 64];

    const int blk   = blockIdx.x;
    const int chunk = blk & (ICH - 1);
    const int b     = (blk >> 5) & (Bb - 1);
    const int dir   = blk >> 8;
    const int t     = threadIdx.x;
    const int lane  = t & 63;
    const int wave  = t >> 6;
    const int l31   = lane & 31;
    const bool lo   = (lane < 32);

    const float* __restrict__ xbase =
        (dir ? point : point_rec) + (size_t)(b * Nn + chunk * 128) * 3;
    const float* __restrict__ ybase =
        (dir ? point_rec : point) + (size_t)b * Nn * 3;

    // ---- stage the full Y row: 16 points per thread ----
    for (int p = t; p < Nn; p += BLOCK) {
        const float* yp = ybase + (size_t)p * 3;
        const unsigned short yh0 = f2bf(yp[0]);
        const unsigned short yh1 = f2bf(yp[1]);
        const unsigned short yh2 = f2bf(yp[2]);
        const float yf0 = bf2f(yh0), yf1 = bf2f(yh1), yf2 = bf2f(yh2);
        const float yy  = fmaf(yf2, yf2, fmaf(yf1, yf1, yf0 * yf0));
        const unsigned short h1 = f2bf(yy);
        const unsigned short h2 = f2bf(yy - bf2f(h1));
        ushort8 v;
        v[0] = yh0; v[1] = yh1; v[2] = yh2; v[3] = h1; v[4] = h2;
        v[5] = 0;   v[6] = 0;   v[7] = 0;
        ytile[p] = v;
    }

    // ---- B fragment: this wave's 32 x-points (fixed for the whole kernel) ----
    const int    i_loc = wave * 32 + l31;          // 0..127 within chunk
    const float* xp    = xbase + (size_t)i_loc * 3;
    const float  a0 = bf2f(f2bf(xp[0]));
    const float  a1 = bf2f(f2bf(xp[1]));
    const float  a2 = bf2f(f2bf(xp[2]));
    ushort8 bu;
    bu[0] = lo ? f2bf(-2.0f * a0) : (unsigned short)0;
    bu[1] = lo ? f2bf(-2.0f * a1) : (unsigned short)0;
    bu[2] = lo ? f2bf(-2.0f * a2) : (unsigned short)0;
    bu[3] = lo ? (unsigned short)0x3F80 : (unsigned short)0;   // bf16 1.0
    bu[4] = lo ? (unsigned short)0x3F80 : (unsigned short)0;
    bu[5] = 0; bu[6] = 0; bu[7] = 0;
    const short8 bfrag = __builtin_bit_cast(short8, bu);

    floatx16 zc;
    #pragma unroll
    for (int q = 0; q < 16; ++q) zc[q] = 0.0f;

    __syncthreads();

    // ---- main loop: 128 MFMAs over the 4096-j row ----
    float m0 = FLT_MAX, m1 = FLT_MAX, m2 = FLT_MAX, m3 = FLT_MAX;
    #pragma unroll 4
    for (int jt = 0; jt < Nn / 32; ++jt) {
        // lanes 32-63 duplicate rows 0-31 (2-way LDS broadcast, free); they
        // feed k=8..15, which multiplies B's zeroed upper half -> harmless.
        const short8 af = __builtin_bit_cast(short8, ytile[jt * 32 + l31]);
        const floatx16 d =
            __builtin_amdgcn_mfma_f32_32x32x16_bf16(af, bfrag, zc, 0, 0, 0);
        m0 = fminf(fminf(d[0],  d[1]),  m0);   // v_min3 each
        m1 = fminf(fminf(d[2],  d[3]),  m1);
        m2 = fminf(fminf(d[4],  d[5]),  m2);
        m3 = fminf(fminf(d[6],  d[7]),  m3);
        m0 = fminf(fminf(d[8],  d[9]),  m0);
        m1 = fminf(fminf(d[10], d[11]), m1);
        m2 = fminf(fminf(d[12], d[13]), m2);
        m3 = fminf(fminf(d[14], d[15]), m3);
    }

    // Per-lane min covers 16 of this column's 32 rows; lane^32 has the rest.
    float mm = fminf(fminf(m0, m1), fminf(m2, m3));
    mm = fminf(mm, __shfl_xor(mm, 32, 64));
    // Both half-waves now hold identical mins -> sum all 64 lanes, halve.
    float v = 0.5f * mm;

    // Additive extras from the lo half only: xx_i and the NLL seg gather.
    if (lo) {
        v = fmaf(a2, a2, fmaf(a1, a1, fmaf(a0, a0, v)));
        if (dir == 0) {
            const int gi = b * Nn + chunk * 128 + i_loc;
            v -= seg_prob[(size_t)gi * NC + (size_t)seg_label[gi]];
        }
    }

    // Block reduction: wave-64 shuffle, then across the 4 waves via LDS.
    for (int off = 32; off > 0; off >>= 1)
        v += __shfl_down(v, off, 64);
    if ((t & 63) == 0) wsum[t >> 6] = v;
    __syncthreads();
    if (t == 0) {
        float s = wsum[0] + wsum[1] + wsum[2] + wsum[3];
        atomicAdd(out, s * (1.0f / (Bb * Nn)));
    }
}

extern "C" void kernel_launch(void* const* d_in, const int* in_sizes, int n_in,
                              void* d_out, int out_size, void* d_ws, size_t ws_size,
                              hipStream_t stream) {
    const float* seg_prob  = (const float*)d_in[0];
    const int*   seg_label = (const int*)d_in[1];
    const float* point_rec = (const float*)d_in[2];
    const float* point     = (const float*)d_in[3];
    float*       out       = (float*)d_out;

    hipMemsetAsync(out, 0, sizeof(float), stream);
    criterion_fused_kernel<<<dim3(2 * Bb * ICH), dim3(BLOCK), 0, stream>>>(
        seg_prob, seg_label, point_rec, point, out);
}

// Round 5
// 71.054 us; speedup vs baseline: 2.0496x; 1.1332x over previous
//
#include <hip/hip_runtime.h>
#include <cfloat>

// Problem constants (fixed by the reference): B=8, N=4096, NUM_CLASS=13, C=3.
constexpr int Bb    = 8;
constexpr int Nn    = 4096;
constexpr int NC    = 13;
constexpr int BLOCK = 512;        // 8 waves; each wave owns 32 i's -> 256 i/block
constexpr int ICH   = Nn / 256;   // 16 i-chunks
// Grid = 2 dir * 8 b * 16 chunk = 256 blocks -> exactly 1 block/CU,
// 2 waves/SIMD. Halves per-CU Y-staging work vs the 256-thread variant.

typedef __attribute__((ext_vector_type(8)))  short          short8;
typedef __attribute__((ext_vector_type(8)))  unsigned short ushort8;
typedef __attribute__((ext_vector_type(16))) float          floatx16;

// fp32 -> bf16 round-to-nearest-even (bit trick; inputs are finite).
static __device__ inline unsigned short f2bf(float f) {
    unsigned u = __builtin_bit_cast(unsigned, f);
    return (unsigned short)((u + 0x7FFFu + ((u >> 16) & 1u)) >> 16);
}
static __device__ inline float bf2f(unsigned short h) {
    return __builtin_bit_cast(float, (unsigned)h << 16);
}

// Single fused kernel (see R2/R3 derivation).
// LDS A-fragment per target point j: {yh0, yh1, yh2, h1, h2, 0, 0, 0} with
// h1+h2 ~= |yhat|^2 (two-term bf16 split of the fp32 value).
// B per wave (32 query points): lanes 0-31 = {-2xh0,-2xh1,-2xh2, 1, 1, 0,0,0},
// lanes 32-63 = 0 (they feed k=8..15, which must not contribute).
// One v_mfma_f32_32x32x16_bf16 per 32-j tile -> t(j,i) = yy - 2 x.y in fp32;
// v_min3 chains reduce the 16 C-values/lane; shfl_xor(32) merges row halves.
// xx (rounded-x, consistent with B) is constant per i -> dropped from the min
// and added back in the block sum, together with the NLL seg gather (dir 0).
__global__ __launch_bounds__(BLOCK)
void criterion_fused_kernel(const float* __restrict__ seg_prob,
                            const int*   __restrict__ seg_label,
                            const float* __restrict__ point_rec,
                            const float* __restrict__ point,
                            float*       __restrict__ out) {
    __shared__ ushort8 ytile[Nn];          // 64 KB
    __shared__ float   wsum[BLOCK / 64];   // 8 waves

    const int blk   = blockIdx.x;
    const int chunk = blk & (ICH - 1);
    const int b     = (blk >> 4) & (Bb - 1);
    const int dir   = blk >> 7;
    const int t     = threadIdx.x;
    const int lane  = t & 63;
    const int wave  = t >> 6;
    const int l31   = lane & 31;
    const bool lo   = (lane < 32);

    const float* __restrict__ xbase =
        (dir ? point : point_rec) + (size_t)(b * Nn + chunk * 256) * 3;
    const float* __restrict__ ybase =
        (dir ? point_rec : point) + (size_t)b * Nn * 3;

    // ---- stage the full Y row: 8 points per thread ----
    #pragma unroll
    for (int q = 0; q < Nn / BLOCK; ++q) {
        const int p = q * BLOCK + t;
        const float* yp = ybase + (size_t)p * 3;
        const unsigned short yh0 = f2bf(yp[0]);
        const unsigned short yh1 = f2bf(yp[1]);
        const unsigned short yh2 = f2bf(yp[2]);
        const float yf0 = bf2f(yh0), yf1 = bf2f(yh1), yf2 = bf2f(yh2);
        const float yy  = fmaf(yf2, yf2, fmaf(yf1, yf1, yf0 * yf0));
        const unsigned short h1 = f2bf(yy);
        const unsigned short h2 = f2bf(yy - bf2f(h1));
        ushort8 v;
        v[0] = yh0; v[1] = yh1; v[2] = yh2; v[3] = h1; v[4] = h2;
        v[5] = 0;   v[6] = 0;   v[7] = 0;
        ytile[p] = v;
    }

    // ---- B fragment: this wave's 32 x-points (fixed for the whole kernel) ----
    const int    i_loc = wave * 32 + l31;          // 0..255 within chunk
    const float* xp    = xbase + (size_t)i_loc * 3;
    const float  a0 = bf2f(f2bf(xp[0]));
    const float  a1 = bf2f(f2bf(xp[1]));
    const float  a2 = bf2f(f2bf(xp[2]));
    ushort8 bu;
    bu[0] = lo ? f2bf(-2.0f * a0) : (unsigned short)0;
    bu[1] = lo ? f2bf(-2.0f * a1) : (unsigned short)0;
    bu[2] = lo ? f2bf(-2.0f * a2) : (unsigned short)0;
    bu[3] = lo ? (unsigned short)0x3F80 : (unsigned short)0;   // bf16 1.0
    bu[4] = lo ? (unsigned short)0x3F80 : (unsigned short)0;
    bu[5] = 0; bu[6] = 0; bu[7] = 0;
    const short8 bfrag = __builtin_bit_cast(short8, bu);

    floatx16 zc;
    #pragma unroll
    for (int q = 0; q < 16; ++q) zc[q] = 0.0f;

    __syncthreads();

    // ---- main loop: 128 MFMAs over the 4096-j row ----
    float m0 = FLT_MAX, m1 = FLT_MAX, m2 = FLT_MAX, m3 = FLT_MAX;
    #pragma unroll 4
    for (int jt = 0; jt < Nn / 32; ++jt) {
        // lanes 32-63 duplicate rows 0-31 of A (2-way LDS broadcast, free);
        // they feed k=8..15, which multiplies B's zeroed upper half.
        const short8 af = __builtin_bit_cast(short8, ytile[jt * 32 + l31]);
        const floatx16 d =
            __builtin_amdgcn_mfma_f32_32x32x16_bf16(af, bfrag, zc, 0, 0, 0);
        m0 = fminf(fminf(d[0],  d[1]),  m0);   // v_min3 each
        m1 = fminf(fminf(d[2],  d[3]),  m1);
        m2 = fminf(fminf(d[4],  d[5]),  m2);
        m3 = fminf(fminf(d[6],  d[7]),  m3);
        m0 = fminf(fminf(d[8],  d[9]),  m0);
        m1 = fminf(fminf(d[10], d[11]), m1);
        m2 = fminf(fminf(d[12], d[13]), m2);
        m3 = fminf(fminf(d[14], d[15]), m3);
    }

    // Per-lane min covers 16 of this column's 32 rows; lane^32 has the rest.
    float mm = fminf(fminf(m0, m1), fminf(m2, m3));
    mm = fminf(mm, __shfl_xor(mm, 32, 64));
    // Both half-waves now hold identical column mins -> sum all lanes, halve.
    float v = 0.5f * mm;

    // Additive extras from the lo half only: xx_i and the NLL seg gather.
    if (lo) {
        v = fmaf(a2, a2, fmaf(a1, a1, fmaf(a0, a0, v)));
        if (dir == 0) {
            const int gi = b * Nn + chunk * 256 + i_loc;
            v -= seg_prob[(size_t)gi * NC + (size_t)seg_label[gi]];
        }
    }

    // Block reduction: wave-64 shuffle, then across the 8 waves via LDS.
    for (int off = 32; off > 0; off >>= 1)
        v += __shfl_down(v, off, 64);
    if ((t & 63) == 0) wsum[t >> 6] = v;
    __syncthreads();
    if (t == 0) {
        float s = 0.0f;
        #pragma unroll
        for (int w = 0; w < BLOCK / 64; ++w) s += wsum[w];
        atomicAdd(out, s * (1.0f / (Bb * Nn)));
    }
}

extern "C" void kernel_launch(void* const* d_in, const int* in_sizes, int n_in,
                              void* d_out, int out_size, void* d_ws, size_t ws_size,
                              hipStream_t stream) {
    const float* seg_prob  = (const float*)d_in[0];
    const int*   seg_label = (const int*)d_in[1];
    const float* point_rec = (const float*)d_in[2];
    const float* point     = (const float*)d_in[3];
    float*       out       = (float*)d_out;

    hipMemsetAsync(out, 0, sizeof(float), stream);
    criterion_fused_kernel<<<dim3(2 * Bb * ICH), dim3(BLOCK), 0, stream>>>(
        seg_prob, seg_label, point_rec, point, out);
}